// Round 11
// baseline (415.970 us; speedup 1.0000x reference)
//
#include <hip/hip_runtime.h>
#include <hip/hip_bf16.h>
#include <cstdint>

// ---------------- problem constants ----------------
#define NN      8192      // nodes
#define OF      64        // out features
#define KC      16        // K-chunks
#define CW      512       // K width per chunk (elements)
#define PSTR    65        // P slab row stride (floats): 64 cols + S
#define RBYTES  1024      // bitmask bytes per row (8192/8)
#define BSTR    520       // B LDS row stride (shorts): 1040B, phase-2-way=free

// ---------------- ws layout (bytes) ----------------
#define OFF_HW  0                           // HW 80x8192 u16       = 1310720
#define OFF_P   1310720                     // P16 16x8192x65 f32   = 34078720
#define OFF_BM  35389440                    // A bitmask 8192x1024B = 8388608

typedef __attribute__((ext_vector_type(8))) short  s16x8;
typedef __attribute__((ext_vector_type(4))) float  f32x4;

__device__ __forceinline__ unsigned short f2bf(float f) {
  unsigned int u = __float_as_uint(f);
  unsigned int r = (u + 0x7FFFu + ((u >> 16) & 1u)) >> 16;   // RNE
  return (unsigned short)r;
}

// ---------------- ka: pack A -> bits, m13-DENSE loads + ballot -------------
// Lane l loads int4 at +16B*l: wave instr = 1KB fully dense (100% sectors).
// Group of 256 elems -> 4 ballots; bit j of ballot_c = element 4j+c.
// Group g's 32B at BM + row*1024 + g*32 = [b0|b1|b2|b3] (u64 each).
__global__ __launch_bounds__(256) void ka_pack(const int* __restrict__ A,
                                               unsigned long long* __restrict__ BM) {
  int t = threadIdx.x;
  int l = t & 63, w = t >> 6;
  int row = blockIdx.x * 4 + w;
  const int* ap = A + (size_t)row * NN + l * 4;
  unsigned long long* bp = BM + (size_t)row * (RBYTES / 8);
#pragma unroll 4
  for (int g = 0; g < 32; ++g) {
    int4 a = *(const int4*)(ap + g * 256);
    unsigned long long b0 = __ballot(a.x != 0);
    unsigned long long b1 = __ballot(a.y != 0);
    unsigned long long b2 = __ballot(a.z != 0);
    unsigned long long b3 = __ballot(a.w != 0);
    if (l == 0) {
      bp[g * 4 + 0] = b0; bp[g * 4 + 1] = b1;
      bp[g * 4 + 2] = b2; bp[g * 4 + 3] = b3;
    }
  }
}

// ---------------- k1: h = X @ W (LDS-tiled fp32) -> fused e/HW write -------
__global__ __launch_bounds__(256) void k1_hw(const float* __restrict__ X,
                                             const float* __restrict__ W,
                                             const float* __restrict__ att,
                                             unsigned short* __restrict__ HW) {
  __shared__ float xs[16 * 516];
  __shared__ float ws[64 * 68];
  int t = threadIdx.x;
  int rb = blockIdx.x * 16;

  {
    const float4* src = (const float4*)(X + (size_t)rb * 512);
#pragma unroll
    for (int s = 0; s < 8; ++s) {
      int lid = s * 256 + t;
      int row = lid >> 7, kseg = lid & 127;
      *(float4*)&xs[row * 516 + kseg * 4] = src[row * 128 + kseg];
    }
  }

  int row = t >> 4, tx = t & 15;
  float4 acc = {0.f, 0.f, 0.f, 0.f};
  for (int kc = 0; kc < 8; ++kc) {
    __syncthreads();
#pragma unroll
    for (int s = 0; s < 4; ++s) {
      int lid = s * 256 + t;
      int k = lid >> 4, cs = lid & 15;
      *(float4*)&ws[k * 68 + cs * 4] =
          *(const float4*)(W + (size_t)(kc * 64 + k) * 64 + cs * 4);
    }
    __syncthreads();
#pragma unroll 16
    for (int k = 0; k < 64; ++k) {
      float x = xs[row * 516 + kc * 64 + k];
      float4 w4 = *(const float4*)&ws[k * 68 + tx * 4];
      acc.x += x * w4.x; acc.y += x * w4.y;
      acc.z += x * w4.z; acc.w += x * w4.w;
    }
  }

  float v = acc.x * att[64 + tx * 4]     + acc.y * att[64 + tx * 4 + 1] +
            acc.z * att[64 + tx * 4 + 2] + acc.w * att[64 + tx * 4 + 3];
#pragma unroll
  for (int m = 8; m > 0; m >>= 1) v += __shfl_xor(v, m, 64);
  float e = expf(v);                 // |r| <~ 21, no overflow

  int j = rb + row;
  unsigned short* hw = HW + j;
  float hv[4] = {acc.x, acc.y, acc.z, acc.w};
#pragma unroll
  for (int c = 0; c < 4; ++c)
    hw[(size_t)(tx * 4 + c) * NN] = f2bf(e * hv[c]);
  if (tx == 0) hw[(size_t)64 * NN] = f2bf(e);   // rows 65..79 never read
}

__device__ __forceinline__ unsigned u4c(uint4 v, int c) {
  return c == 0 ? v.x : c == 1 ? v.y : c == 2 ? v.z : v.w;
}
// half-word pair from two 1-bit values (bit0 of a, bit0 of b) -> bf16 {0,1}x2
__device__ __forceinline__ unsigned mk2(unsigned a, unsigned b) {
  return ((a & 1u) | ((b & 1u) << 16)) * 0x3F80u;
}

// ---------------- k3: register-resident ballot-bit A x padded-LDS B -------
// Frag (s,ks,q): elements E..E+7, E = kc*512 + s*64 + ks*32 + q*8.
// In ballot layout: group = s>>2, J = (s&3)*16 + ks*8 + q*2; need bits
// {J,J+1} of b0..b3 -> elements (E+c, E+4+c). All-static except q*2 shift.
__global__ __launch_bounds__(256, 2) void k3_gat(const unsigned char* __restrict__ BM,
                                                 const unsigned short* __restrict__ HW,
                                                 float* __restrict__ P) {
  __shared__ unsigned short bt[65 * BSTR];  // 67600 B -> 2 blocks/CU

  int t = threadIdx.x;
  int kc = blockIdx.x & 15;                 // XCD-affine B slice
  int mg = blockIdx.x >> 4;                 // 0..63
  int lane = t & 63, w = t >> 6;
  int l15 = lane & 15, q = lane >> 4;
  int k0 = kc * CW;
  int rowM = mg * 128;
  int q2 = q * 2;

  // upfront A-bit load: 64B per lane-row = groups {2kc, 2kc+1}
  uint4 abits[2][4];
#pragma unroll
  for (int mt = 0; mt < 2; ++mt) {
    const uint4* p = (const uint4*)(BM +
        (size_t)(rowM + w * 32 + mt * 16 + l15) * RBYTES + kc * 64);
#pragma unroll
    for (int i = 0; i < 4; ++i) abits[mt][i] = p[i];
  }

  // stage B, padded stride (no swizzle)
#pragma unroll
  for (int rds = 0; rds < 16; ++rds) {
    int lid = rds * 256 + t;
    int row = lid >> 6, ch = lid & 63;
    uint4 v = *(const uint4*)(HW + (size_t)row * NN + k0 + ch * 8);
    *(uint4*)&bt[row * BSTR + ch * 8] = v;
  }
  if (t < 64) {
    uint4 v = *(const uint4*)(HW + (size_t)64 * NN + k0 + t * 8);
    *(uint4*)&bt[64 * BSTR + t * 8] = v;
  }
  __syncthreads();                          // the ONLY barrier

  // B ds_read byte bases: 1040*row + 16*(ks*4+q) (+128*s at use site)
  int bb[4][2];
#pragma unroll
  for (int tt = 0; tt < 4; ++tt)
#pragma unroll
    for (int ks = 0; ks < 2; ++ks)
      bb[tt][ks] = ((tt * 16 + l15) * BSTR + (ks * 4 + q) * 8) * 2;
  int eb0 = (64 * BSTR + q * 8) * 2;
  int eb1 = (64 * BSTR + (4 + q) * 8) * 2;

  f32x4 acc[2][5];
#pragma unroll
  for (int mt = 0; mt < 2; ++mt)
#pragma unroll
    for (int tt = 0; tt < 5; ++tt) acc[mt][tt] = 0.f;
  const s16x8 zero8 = {0, 0, 0, 0, 0, 0, 0, 0};

#pragma unroll
  for (int s = 0; s < 8; ++s) {
    int base = (s >> 2) * 2;                // uint4 pair for this group
    int h = ((s & 3) >= 2) ? 1 : 0;        // u64 half holding bit J
    int bpc = (s & 1) * 16;                 // + ks*8 + q*2 below

    s16x8 af[2][2];
#pragma unroll
    for (int ks = 0; ks < 2; ++ks) {
      int sh = bpc + ks * 8;                // static part of shift
#pragma unroll
      for (int mt = 0; mt < 2; ++mt) {
        unsigned v0 = u4c(abits[mt][base],     0 + h) >> (sh + q2);
        unsigned v1 = u4c(abits[mt][base],     2 + h) >> (sh + q2);
        unsigned v2 = u4c(abits[mt][base + 1], 0 + h) >> (sh + q2);
        unsigned v3 = u4c(abits[mt][base + 1], 2 + h) >> (sh + q2);
        union { unsigned u[4]; s16x8 v; } fr;
        fr.u[0] = mk2(v0, v1);              // elements E+0, E+1
        fr.u[1] = mk2(v2, v3);              // E+2, E+3
        fr.u[2] = mk2(v0 >> 1, v1 >> 1);    // E+4, E+5
        fr.u[3] = mk2(v2 >> 1, v3 >> 1);    // E+6, E+7
        af[mt][ks] = fr.v;
      }
    }

    int so = s * 128;
#pragma unroll
    for (int ks = 0; ks < 2; ++ks) {
#pragma unroll
      for (int tt = 0; tt < 4; ++tt) {
        s16x8 b = *(const s16x8*)((char*)bt + bb[tt][ks] + so);
#pragma unroll
        for (int mt = 0; mt < 2; ++mt)
          acc[mt][tt] = __builtin_amdgcn_mfma_f32_16x16x32_bf16(af[mt][ks], b, acc[mt][tt], 0, 0, 0);
      }
      s16x8 b4 = *(const s16x8*)((char*)bt + (ks ? eb1 : eb0) + so);
      b4 = (l15 == 0) ? b4 : zero8;
#pragma unroll
      for (int mt = 0; mt < 2; ++mt)
        acc[mt][4] = __builtin_amdgcn_mfma_f32_16x16x32_bf16(af[mt][ks], b4, acc[mt][4], 0, 0, 0);
    }
  }

  // epilogue: C/D layout col=l15, row=q*4+rg
  float* Pp = P + (size_t)kc * NN * PSTR;
#pragma unroll
  for (int mt = 0; mt < 2; ++mt) {
    int rb = rowM + w * 32 + mt * 16 + q * 4;
#pragma unroll
    for (int tt = 0; tt < 4; ++tt)
#pragma unroll
      for (int rg = 0; rg < 4; ++rg)
        Pp[(size_t)(rb + rg) * PSTR + tt * 16 + l15] = acc[mt][tt][rg];
    if (l15 == 0)
#pragma unroll
      for (int rg = 0; rg < 4; ++rg)
        Pp[(size_t)(rb + rg) * PSTR + 64] = acc[mt][4][rg];
  }
}

// ---------------- k4: reduce 16 slabs + normalize + ELU ----------------
__global__ __launch_bounds__(256) void k4_fin(const float* __restrict__ P,
                                              float* __restrict__ out) {
  int g = blockIdx.x * 256 + threadIdx.x;          // 524288
  int i = g >> 6, c = g & 63;
  float num = 0.f, S = 0.f;
#pragma unroll
  for (int kc = 0; kc < KC; ++kc) {
    const float* p = P + (size_t)kc * NN * PSTR + (size_t)i * PSTR;
    num += p[c];
    S   += p[64];
  }
  float x = num / S;
  out[g] = x > 0.f ? x : expm1f(x);
}

extern "C" void kernel_launch(void* const* d_in, const int* in_sizes, int n_in,
                              void* d_out, int out_size, void* d_ws, size_t ws_size,
                              hipStream_t stream) {
  const float* X  = (const float*)d_in[0];   // 8192x512
  const int*   A  = (const int*)d_in[1];     // 8192x8192
  const float* W  = (const float*)d_in[2];   // 512x64
  const float* av = (const float*)d_in[3];   // 128x1
  float* out = (float*)d_out;

  char* ws = (char*)d_ws;
  unsigned short*     HW = (unsigned short*)(ws + OFF_HW);
  float*              P  = (float*)(ws + OFF_P);
  unsigned long long* BM = (unsigned long long*)(ws + OFF_BM);

  ka_pack<<<NN / 4, 256, 0, stream>>>(A, BM);
  k1_hw<<<NN / 16, 256, 0, stream>>>(X, W, av, HW);
  k3_gat<<<64 * KC, 256, 0, stream>>>((const unsigned char*)BM, HW, P);
  k4_fin<<<(size_t)NN * OF / 256, 256, 0, stream>>>(P, out);
}

// Round 12
// 390.794 us; speedup vs baseline: 1.0644x; 1.0644x over previous
//
#include <hip/hip_runtime.h>
#include <hip/hip_bf16.h>
#include <cstdint>

// ---------------- problem constants ----------------
#define NN      8192      // nodes
#define OF      64        // out features
#define KC      16        // K-chunks
#define CW      512       // K width per chunk (elements)
#define ASTR    72        // A LDS tile stride (shorts)
#define PSTR    65        // P slab row stride (floats): 64 cols + S

// ---------------- ws layout (bytes) ----------------
#define OFF_HW  0                           // HW 80x8192 u16       = 1310720
#define OFF_P   1310720                     // P16 16x8192x65 f32   = 34078720

typedef __attribute__((ext_vector_type(8))) short  s16x8;
typedef __attribute__((ext_vector_type(4))) float  f32x4;

__device__ __forceinline__ unsigned short f2bf(float f) {
  unsigned int u = __float_as_uint(f);
  unsigned int r = (u + 0x7FFFu + ((u >> 16) & 1u)) >> 16;   // RNE
  return (unsigned short)r;
}

// ---------------- k1: h = X @ W (LDS-tiled fp32) -> fused e/HW write -------
__global__ __launch_bounds__(256) void k1_hw(const float* __restrict__ X,
                                             const float* __restrict__ W,
                                             const float* __restrict__ att,
                                             unsigned short* __restrict__ HW) {
  __shared__ float xs[16 * 516];
  __shared__ float ws[64 * 68];
  int t = threadIdx.x;
  int rb = blockIdx.x * 16;

  {
    const float4* src = (const float4*)(X + (size_t)rb * 512);
#pragma unroll
    for (int s = 0; s < 8; ++s) {
      int lid = s * 256 + t;
      int row = lid >> 7, kseg = lid & 127;
      *(float4*)&xs[row * 516 + kseg * 4] = src[row * 128 + kseg];
    }
  }

  int row = t >> 4, tx = t & 15;
  float4 acc = {0.f, 0.f, 0.f, 0.f};
  for (int kc = 0; kc < 8; ++kc) {
    __syncthreads();
#pragma unroll
    for (int s = 0; s < 4; ++s) {
      int lid = s * 256 + t;
      int k = lid >> 4, cs = lid & 15;
      *(float4*)&ws[k * 68 + cs * 4] =
          *(const float4*)(W + (size_t)(kc * 64 + k) * 64 + cs * 4);
    }
    __syncthreads();
#pragma unroll 16
    for (int k = 0; k < 64; ++k) {
      float x = xs[row * 516 + kc * 64 + k];
      float4 w4 = *(const float4*)&ws[k * 68 + tx * 4];
      acc.x += x * w4.x; acc.y += x * w4.y;
      acc.z += x * w4.z; acc.w += x * w4.w;
    }
  }

  float v = acc.x * att[64 + tx * 4]     + acc.y * att[64 + tx * 4 + 1] +
            acc.z * att[64 + tx * 4 + 2] + acc.w * att[64 + tx * 4 + 3];
#pragma unroll
  for (int m = 8; m > 0; m >>= 1) v += __shfl_xor(v, m, 64);
  float e = expf(v);                 // |r| <~ 21, no overflow

  int j = rb + row;
  unsigned short* hw = HW + j;
  float hv[4] = {acc.x, acc.y, acc.z, acc.w};
#pragma unroll
  for (int c = 0; c < 4; ++c)
    hw[(size_t)(tx * 4 + c) * NN] = f2bf(e * hv[c]);
  if (tx == 0) hw[(size_t)64 * NN] = f2bf(e);   // rows 65..79 never read
}

// ---------------- k3: wave-autonomous A-stream; NO per-step barriers -------
// Identical to the round-8 (passing, 396us) kernel EXCEPT the per-step
// lds_barrier() pairs are deleted: the A-tile regions are wave-private
// (wave w writes AND reads only rows w*16..w*16+15), so only in-wave
// lgkmcnt ordering (compiler-inserted) is required. Waves free-run their
// load->cvt->LDS->MFMA pipelines; A loads stay in flight continuously.
__global__ __launch_bounds__(256, 2) void k3_gat(const int* __restrict__ A,
                                                 const unsigned short* __restrict__ HW,
                                                 float* __restrict__ P) {
  __shared__ unsigned short bt[65 * 512];   // 66560 B, XOR-swizzled B
  __shared__ unsigned short at[64 * ASTR];  //  9216 B, per-wave A regions

  int t = threadIdx.x;
  int kc = blockIdx.x & 15;                 // XCD-affine B slice
  int mg = blockIdx.x >> 4;                 // 0..127
  int lane = t & 63, w = t >> 6;
  int l15 = lane & 15, q = lane >> 4;
  int k0 = kc * CW;
  int rowM = mg * 64;

  // A prefetch pointers: instr i covers rows w*16+i*4+q, 16 lanes x 16B contig
  const int* ap[4];
#pragma unroll
  for (int i = 0; i < 4; ++i)
    ap[i] = A + (size_t)(rowM + w * 16 + i * 4 + q) * NN + k0 + l15 * 4;

  int4 av[3][4];
#pragma unroll
  for (int i = 0; i < 4; ++i) av[0][i] = *(const int4*)(ap[i]);        // s=0
#pragma unroll
  for (int i = 0; i < 4; ++i) av[1][i] = *(const int4*)(ap[i] + 64);   // s=1

  // stage B swizzled: chunk ch of row goes to position ch ^ (row & 7)
#pragma unroll
  for (int rds = 0; rds < 16; ++rds) {
    int lid = rds * 256 + t;
    int row = lid >> 6, ch = lid & 63;
    uint4 v = *(const uint4*)(HW + (size_t)row * NN + k0 + ch * 8);
    *(uint4*)&bt[row * 512 + ((ch ^ (row & 7)) * 8)] = v;
  }
  if (t < 64) {                             // row 64 (e-row), unswizzled
    uint4 v = *(const uint4*)(HW + (size_t)64 * NN + k0 + t * 8);
    *(uint4*)&bt[64 * 512 + t * 8] = v;
  }
  __syncthreads();                          // the ONLY barrier

  // B ds_read byte-address bases (round-8-verified conflict-free)
  int swz = l15 & 7;
  int bb[4][2];
#pragma unroll
  for (int tt = 0; tt < 4; ++tt)
#pragma unroll
    for (int ks = 0; ks < 2; ++ks)
      bb[tt][ks] = ((tt * 16 + l15) * 512 + (((ks * 4 + q) ^ swz) * 8)) * 2;
  int eb0 = (64 * 512 + q * 8) * 2;
  int eb1 = (64 * 512 + (4 + q) * 8) * 2;
  int ab  = ((w * 16 + l15) * ASTR + q * 8) * 2;

  f32x4 acc[5];
#pragma unroll
  for (int tt = 0; tt < 5; ++tt) acc[tt] = 0.f;
  const s16x8 zero8 = {0, 0, 0, 0, 0, 0, 0, 0};

#pragma unroll
  for (int s = 0; s < 8; ++s) {
    // write A(s) -> wave-private tile region (cvt int{0,1} -> packed bf16)
#pragma unroll
    for (int i = 0; i < 4; ++i) {
      int4 vv = av[s % 3][i];
      uint2 p;
      p.x = (unsigned)(vv.x | (vv.y << 16)) * 0x3F80u;
      p.y = (unsigned)(vv.z | (vv.w << 16)) * 0x3F80u;
      *(uint2*)((char*)at + (((w * 16 + i * 4 + q) * ASTR + l15 * 4) * 2)) = p;
    }
    if (s < 6) {
#pragma unroll
      for (int i = 0; i < 4; ++i)
        av[(s + 2) % 3][i] = *(const int4*)(ap[i] + (s + 2) * 64);
    }

    // wave-local read-back (lgkmcnt ordering only; no s_barrier)
    s16x8 af0 = *(const s16x8*)((char*)at + ab);
    s16x8 af1 = *(const s16x8*)((char*)at + ab + 64);
    int so = s * 128;                       // step byte offset within B row
#pragma unroll
    for (int ks = 0; ks < 2; ++ks) {
      s16x8 af = ks ? af1 : af0;
#pragma unroll
      for (int tt = 0; tt < 4; ++tt) {
        s16x8 b = *(const s16x8*)((char*)bt + bb[tt][ks] + so);
        acc[tt] = __builtin_amdgcn_mfma_f32_16x16x32_bf16(af, b, acc[tt], 0, 0, 0);
      }
      s16x8 b4 = *(const s16x8*)((char*)bt + (ks ? eb1 : eb0) + so);
      b4 = (l15 == 0) ? b4 : zero8;
      acc[4] = __builtin_amdgcn_mfma_f32_16x16x32_bf16(af, b4, acc[4], 0, 0, 0);
    }
  }

  // epilogue: C/D layout col=l15, row=q*4+rg
  float* Pp = P + (size_t)kc * NN * PSTR;
  int rb = rowM + w * 16 + q * 4;
#pragma unroll
  for (int tt = 0; tt < 4; ++tt)
#pragma unroll
    for (int rg = 0; rg < 4; ++rg)
      Pp[(size_t)(rb + rg) * PSTR + tt * 16 + l15] = acc[tt][rg];
  if (l15 == 0)
#pragma unroll
    for (int rg = 0; rg < 4; ++rg)
      Pp[(size_t)(rb + rg) * PSTR + 64] = acc[4][rg];
}

// ---------------- k4: reduce 16 slabs + normalize + ELU ----------------
__global__ __launch_bounds__(256) void k4_fin(const float* __restrict__ P,
                                              float* __restrict__ out) {
  int g = blockIdx.x * 256 + threadIdx.x;          // 524288
  int i = g >> 6, c = g & 63;
  float num = 0.f, S = 0.f;
#pragma unroll
  for (int kc = 0; kc < KC; ++kc) {
    const float* p = P + (size_t)kc * NN * PSTR + (size_t)i * PSTR;
    num += p[c];
    S   += p[64];
  }
  float x = num / S;
  out[g] = x > 0.f ? x : expm1f(x);
}

extern "C" void kernel_launch(void* const* d_in, const int* in_sizes, int n_in,
                              void* d_out, int out_size, void* d_ws, size_t ws_size,
                              hipStream_t stream) {
  const float* X  = (const float*)d_in[0];   // 8192x512
  const int*   A  = (const int*)d_in[1];     // 8192x8192
  const float* W  = (const float*)d_in[2];   // 512x64
  const float* av = (const float*)d_in[3];   // 128x1
  float* out = (float*)d_out;

  char* ws = (char*)d_ws;
  unsigned short* HW = (unsigned short*)(ws + OFF_HW);
  float*          P  = (float*)(ws + OFF_P);

  k1_hw<<<NN / 16, 256, 0, stream>>>(X, W, av, HW);
  k3_gat<<<128 * KC, 256, 0, stream>>>(A, HW, P);
  k4_fin<<<(size_t)NN * OF / 256, 256, 0, stream>>>(P, out);
}

// Round 13
// 390.756 us; speedup vs baseline: 1.0645x; 1.0001x over previous
//
#include <hip/hip_runtime.h>
#include <hip/hip_bf16.h>
#include <cstdint>

// ---------------- problem constants ----------------
#define NN      8192      // nodes
#define OF      64        // out features
#define KC      16        // K-chunks
#define CW      512       // K width per chunk (elements)
#define ASTR    72        // A LDS tile stride (shorts)
#define PSTR    65        // P slab row stride (floats): 64 cols + S

// ---------------- ws layout (bytes) ----------------
#define OFF_HW  0                           // HW 80x8192 u16       = 1310720
#define OFF_P   1310720                     // P16 16x8192x65 f32   = 34078720

typedef __attribute__((ext_vector_type(8))) short  s16x8;
typedef __attribute__((ext_vector_type(4))) float  f32x4;

__device__ __forceinline__ unsigned short f2bf(float f) {
  unsigned int u = __float_as_uint(f);
  unsigned int r = (u + 0x7FFFu + ((u >> 16) & 1u)) >> 16;   // RNE
  return (unsigned short)r;
}

// ---------------- k1: h = X @ W (LDS-tiled fp32) -> fused e/HW write -------
__global__ __launch_bounds__(256) void k1_hw(const float* __restrict__ X,
                                             const float* __restrict__ W,
                                             const float* __restrict__ att,
                                             unsigned short* __restrict__ HW) {
  __shared__ float xs[16 * 516];
  __shared__ float ws[64 * 68];
  int t = threadIdx.x;
  int rb = blockIdx.x * 16;

  {
    const float4* src = (const float4*)(X + (size_t)rb * 512);
#pragma unroll
    for (int s = 0; s < 8; ++s) {
      int lid = s * 256 + t;
      int row = lid >> 7, kseg = lid & 127;
      *(float4*)&xs[row * 516 + kseg * 4] = src[row * 128 + kseg];
    }
  }

  int row = t >> 4, tx = t & 15;
  float4 acc = {0.f, 0.f, 0.f, 0.f};
  for (int kc = 0; kc < 8; ++kc) {
    __syncthreads();
#pragma unroll
    for (int s = 0; s < 4; ++s) {
      int lid = s * 256 + t;
      int k = lid >> 4, cs = lid & 15;
      *(float4*)&ws[k * 68 + cs * 4] =
          *(const float4*)(W + (size_t)(kc * 64 + k) * 64 + cs * 4);
    }
    __syncthreads();
#pragma unroll 16
    for (int k = 0; k < 64; ++k) {
      float x = xs[row * 516 + kc * 64 + k];
      float4 w4 = *(const float4*)&ws[k * 68 + tx * 4];
      acc.x += x * w4.x; acc.y += x * w4.y;
      acc.z += x * w4.z; acc.w += x * w4.w;
    }
  }

  float v = acc.x * att[64 + tx * 4]     + acc.y * att[64 + tx * 4 + 1] +
            acc.z * att[64 + tx * 4 + 2] + acc.w * att[64 + tx * 4 + 3];
#pragma unroll
  for (int m = 8; m > 0; m >>= 1) v += __shfl_xor(v, m, 64);
  float e = expf(v);                 // |r| <~ 21, no overflow

  int j = rb + row;
  unsigned short* hw = HW + j;
  float hv[4] = {acc.x, acc.y, acc.z, acc.w};
#pragma unroll
  for (int c = 0; c < 4; ++c)
    hw[(size_t)(tx * 4 + c) * NN] = f2bf(e * hv[c]);
  if (tx == 0) hw[(size_t)64 * NN] = f2bf(e);   // rows 65..79 never read
}

// ---------------- k3: full-depth A preload; loop has ZERO global loads -----
// r12 structure (wave-private A tile, no per-step barriers, swizzled
// resident B) but the whole 32KB/wave A-slice is issued as one 32-deep
// dwordx4 burst up front (128 VGPRs; LDS caps us at 2 blocks/CU = 2
// waves/SIMD so the 256-VGPR budget absorbs it). K-loop = LDS+VALU+MFMA
// only -- no vmcnt waits anywhere after the barrier.
__global__ __launch_bounds__(256, 2) void k3_gat(const int* __restrict__ A,
                                                 const unsigned short* __restrict__ HW,
                                                 float* __restrict__ P) {
  __shared__ unsigned short bt[65 * 512];   // 66560 B, XOR-swizzled B
  __shared__ unsigned short at[64 * ASTR];  //  9216 B, per-wave A regions

  int t = threadIdx.x;
  int kc = blockIdx.x & 15;                 // XCD-affine B slice
  int mg = blockIdx.x >> 4;                 // 0..127
  int lane = t & 63, w = t >> 6;
  int l15 = lane & 15, q = lane >> 4;
  int k0 = kc * CW;
  int rowM = mg * 64;

  // A pointers: instr i covers rows w*16+i*4+q, 16 lanes x 16B contiguous
  const int* ap[4];
#pragma unroll
  for (int i = 0; i < 4; ++i)
    ap[i] = A + (size_t)(rowM + w * 16 + i * 4 + q) * NN + k0 + l15 * 4;

  // full-depth preload: all 8 steps x 4 row-groups, one 32-deep burst
  int4 av[8][4];
#pragma unroll
  for (int s = 0; s < 8; ++s)
#pragma unroll
    for (int i = 0; i < 4; ++i)
      av[s][i] = *(const int4*)(ap[i] + s * 64);

  // stage B swizzled: chunk ch of row goes to position ch ^ (row & 7)
#pragma unroll
  for (int rds = 0; rds < 16; ++rds) {
    int lid = rds * 256 + t;
    int row = lid >> 6, ch = lid & 63;
    uint4 v = *(const uint4*)(HW + (size_t)row * NN + k0 + ch * 8);
    *(uint4*)&bt[row * 512 + ((ch ^ (row & 7)) * 8)] = v;
  }
  if (t < 64) {                             // row 64 (e-row), unswizzled
    uint4 v = *(const uint4*)(HW + (size_t)64 * NN + k0 + t * 8);
    *(uint4*)&bt[64 * 512 + t * 8] = v;
  }
  __syncthreads();                          // the ONLY barrier

  // B ds_read byte-address bases (round-8-verified conflict-free)
  int swz = l15 & 7;
  int bb[4][2];
#pragma unroll
  for (int tt = 0; tt < 4; ++tt)
#pragma unroll
    for (int ks = 0; ks < 2; ++ks)
      bb[tt][ks] = ((tt * 16 + l15) * 512 + (((ks * 4 + q) ^ swz) * 8)) * 2;
  int eb0 = (64 * 512 + q * 8) * 2;
  int eb1 = (64 * 512 + (4 + q) * 8) * 2;
  int ab  = ((w * 16 + l15) * ASTR + q * 8) * 2;

  f32x4 acc[5];
#pragma unroll
  for (int tt = 0; tt < 5; ++tt) acc[tt] = 0.f;
  const s16x8 zero8 = {0, 0, 0, 0, 0, 0, 0, 0};

#pragma unroll
  for (int s = 0; s < 8; ++s) {
    // write A(s) -> wave-private tile region (cvt int{0,1} -> packed bf16)
#pragma unroll
    for (int i = 0; i < 4; ++i) {
      int4 vv = av[s][i];
      uint2 p;
      p.x = (unsigned)(vv.x | (vv.y << 16)) * 0x3F80u;
      p.y = (unsigned)(vv.z | (vv.w << 16)) * 0x3F80u;
      *(uint2*)((char*)at + (((w * 16 + i * 4 + q) * ASTR + l15 * 4) * 2)) = p;
    }

    // wave-local read-back (lgkmcnt ordering only; no s_barrier)
    s16x8 af0 = *(const s16x8*)((char*)at + ab);
    s16x8 af1 = *(const s16x8*)((char*)at + ab + 64);
    int so = s * 128;                       // step byte offset within B row
#pragma unroll
    for (int ks = 0; ks < 2; ++ks) {
      s16x8 af = ks ? af1 : af0;
#pragma unroll
      for (int tt = 0; tt < 4; ++tt) {
        s16x8 b = *(const s16x8*)((char*)bt + bb[tt][ks] + so);
        acc[tt] = __builtin_amdgcn_mfma_f32_16x16x32_bf16(af, b, acc[tt], 0, 0, 0);
      }
      s16x8 b4 = *(const s16x8*)((char*)bt + (ks ? eb1 : eb0) + so);
      b4 = (l15 == 0) ? b4 : zero8;
      acc[4] = __builtin_amdgcn_mfma_f32_16x16x32_bf16(af, b4, acc[4], 0, 0, 0);
    }
  }

  // epilogue: C/D layout col=l15, row=q*4+rg
  float* Pp = P + (size_t)kc * NN * PSTR;
  int rb = rowM + w * 16 + q * 4;
#pragma unroll
  for (int tt = 0; tt < 4; ++tt)
#pragma unroll
    for (int rg = 0; rg < 4; ++rg)
      Pp[(size_t)(rb + rg) * PSTR + tt * 16 + l15] = acc[tt][rg];
  if (l15 == 0)
#pragma unroll
    for (int rg = 0; rg < 4; ++rg)
      Pp[(size_t)(rb + rg) * PSTR + 64] = acc[4][rg];
}

// ---------------- k4: reduce 16 slabs + normalize + ELU ----------------
__global__ __launch_bounds__(256) void k4_fin(const float* __restrict__ P,
                                              float* __restrict__ out) {
  int g = blockIdx.x * 256 + threadIdx.x;          // 524288
  int i = g >> 6, c = g & 63;
  float num = 0.f, S = 0.f;
#pragma unroll
  for (int kc = 0; kc < KC; ++kc) {
    const float* p = P + (size_t)kc * NN * PSTR + (size_t)i * PSTR;
    num += p[c];
    S   += p[64];
  }
  float x = num / S;
  out[g] = x > 0.f ? x : expm1f(x);
}

extern "C" void kernel_launch(void* const* d_in, const int* in_sizes, int n_in,
                              void* d_out, int out_size, void* d_ws, size_t ws_size,
                              hipStream_t stream) {
  const float* X  = (const float*)d_in[0];   // 8192x512
  const int*   A  = (const int*)d_in[1];     // 8192x8192
  const float* W  = (const float*)d_in[2];   // 512x64
  const float* av = (const float*)d_in[3];   // 128x1
  float* out = (float*)d_out;

  char* ws = (char*)d_ws;
  unsigned short* HW = (unsigned short*)(ws + OFF_HW);
  float*          P  = (float*)(ws + OFF_P);

  k1_hw<<<NN / 16, 256, 0, stream>>>(X, W, av, HW);
  k3_gat<<<128 * KC, 256, 0, stream>>>(A, HW, P);
  k4_fin<<<(size_t)NN * OF / 256, 256, 0, stream>>>(P, out);
}